// Round 3
// baseline (264.397 us; speedup 1.0000x reference)
//
#include <hip/hip_runtime.h>

#define F0 128
#define F1 64
#define F2 32

__device__ __forceinline__ int rfl(int v) { return __builtin_amdgcn_readfirstlane(v); }

// bf16 helpers (RNE)
__device__ __forceinline__ unsigned short f2b(float f) {
    unsigned u = __float_as_uint(f);
    return (unsigned short)((u + 0x7fffu + ((u >> 16) & 1u)) >> 16);
}
__device__ __forceinline__ float b2f(unsigned short u) {
    return __uint_as_float(((unsigned)u) << 16);
}

// accumulate 8 bf16 (packed in a uint4) into 8 float accumulators
__device__ __forceinline__ void acc8(float* a, uint4 v) {
    a[0] += __uint_as_float(v.x << 16);
    a[1] += __uint_as_float(v.x & 0xffff0000u);
    a[2] += __uint_as_float(v.y << 16);
    a[3] += __uint_as_float(v.y & 0xffff0000u);
    a[4] += __uint_as_float(v.z << 16);
    a[5] += __uint_as_float(v.z & 0xffff0000u);
    a[6] += __uint_as_float(v.w << 16);
    a[7] += __uint_as_float(v.w & 0xffff0000u);
}

// ---------------- degree ----------------
__global__ void deg_count(const int* __restrict__ dst, int* __restrict__ deg, int E) {
    int e = blockIdx.x * blockDim.x + threadIdx.x;
    if (e < E) atomicAdd(&deg[dst[e]], 1);
}

// ---------------- scan (3 kernels; round-9 post-mortem: single-block fused scan
// was 135 us latency-bound on one CU — multi-block version is ~5 us) ----------------
__global__ void scan1(const int* __restrict__ deg, float* __restrict__ dinv,
                      int* __restrict__ rowptr, int* __restrict__ bsum, int N) {
    __shared__ int s[256];
    int i = blockIdx.x * 256 + threadIdx.x;
    int v = (i < N) ? deg[i] : 0;
    if (i < N) dinv[i] = rsqrtf((float)(v + 1));  // +1 self-loop
    s[threadIdx.x] = v;
    __syncthreads();
    for (int off = 1; off < 256; off <<= 1) {
        int t = 0;
        if (threadIdx.x >= off) t = s[threadIdx.x - off];
        __syncthreads();
        if (threadIdx.x >= off) s[threadIdx.x] += t;
        __syncthreads();
    }
    if (i < N) rowptr[i] = s[threadIdx.x] - v;
    if (threadIdx.x == 255) bsum[blockIdx.x] = s[255];
}

__global__ void scan2(int* __restrict__ bsum, int* __restrict__ boff, int nb) {
    __shared__ int s[256];
    int v = (threadIdx.x < nb) ? bsum[threadIdx.x] : 0;
    s[threadIdx.x] = v;
    __syncthreads();
    for (int off = 1; off < 256; off <<= 1) {
        int t = 0;
        if (threadIdx.x >= off) t = s[threadIdx.x - off];
        __syncthreads();
        if (threadIdx.x >= off) s[threadIdx.x] += t;
        __syncthreads();
    }
    if (threadIdx.x < nb) boff[threadIdx.x] = s[threadIdx.x] - v;
}

__global__ void scan3(int* __restrict__ rowptr, const int* __restrict__ boff,
                      int* __restrict__ cursor, int N) {
    int i = blockIdx.x * 256 + threadIdx.x;
    if (i < N) {
        int v = rowptr[i] + boff[blockIdx.x];
        rowptr[i] = v;
        cursor[i] = v;
    }
}

// ---------------- bucket, XCD-pinned by dst partition (blockIdx&7) ----------------
__global__ __launch_bounds__(256) void bucket8(const int* __restrict__ src,
                                               const int* __restrict__ dst,
                                               int* __restrict__ cursor,
                                               int* __restrict__ csr, int E, int N) {
    int part = blockIdx.x & 7;
    int g = blockIdx.x >> 3;
    int G = gridDim.x >> 3;
    int plo = (int)(((long long)N * part) >> 3);
    int phi = (int)(((long long)N * (part + 1)) >> 3);
    for (int e = g * 256 + threadIdx.x; e < E; e += G * 256) {
        int d = dst[e];
        if (d >= plo && d < phi) {
            int pos = atomicAdd(&cursor[d], 1);
            csr[pos] = src[e];
        }
    }
}

// ---------------- GEMM1: xws1b = bf16((x @ W1) * dinv[row])   [N,128]x[128,64] -------
// k-loop bound `kb` is a RUNTIME arg so the compiler cannot fully unroll
// (round-5 post-mortem: full unroll -> 256 VGPR -> 750 MB scratch spill).
__global__ __launch_bounds__(256) void gemm1(const float* __restrict__ x,
                                             const float* __restrict__ W1,
                                             const float* __restrict__ dinv,
                                             unsigned short* __restrict__ xws1b,
                                             int N, int kb) {
    __shared__ float sx[64][132];
    __shared__ float sW[64][64];
    int tid = threadIdx.x;
    int row0 = blockIdx.x * 64;

    for (int i = tid; i < 2048; i += 256) {
        int r = i >> 5, kq = i & 31;
        int gr = row0 + r;
        float4 v = make_float4(0.f, 0.f, 0.f, 0.f);
        if (gr < N) v = ((const float4*)(x + (size_t)gr * F0))[kq];
        *(float4*)(&sx[r][kq << 2]) = v;
    }

    int tx = tid & 15, ty = tid >> 4;
    int c0 = tx * 4, r0 = ty * 4;
    float acc[4][4] = {};

    const float4* W4 = (const float4*)W1;
    float4* sW4 = (float4*)(&sW[0][0]);

    for (int p = 0; p < 2; ++p) {
        if (p) __syncthreads();
        for (int i = tid; i < 1024; i += 256) sW4[i] = W4[p * 1024 + i];
        __syncthreads();
        int kbase = p * 64;
        for (int k = 0; k < kb; k += 4) {
            float a[4][4], b[4][4];
            #pragma unroll
            for (int rr = 0; rr < 4; ++rr)
                *(float4*)&a[rr][0] = *(const float4*)&sx[r0 + rr][kbase + k];
            #pragma unroll
            for (int j = 0; j < 4; ++j)
                *(float4*)&b[j][0] = *(const float4*)&sW[k + j][c0];
            #pragma unroll
            for (int j = 0; j < 4; ++j)
                #pragma unroll
                for (int rr = 0; rr < 4; ++rr)
                    #pragma unroll
                    for (int cc = 0; cc < 4; ++cc)
                        acc[rr][cc] += a[rr][j] * b[j][cc];
        }
    }

    #pragma unroll
    for (int rr = 0; rr < 4; ++rr) {
        int gr = row0 + r0 + rr;
        if (gr < N) {
            float s = dinv[gr];
            ushort4 o;
            o.x = f2b(acc[rr][0] * s); o.y = f2b(acc[rr][1] * s);
            o.z = f2b(acc[rr][2] * s); o.w = f2b(acc[rr][3] * s);
            *(ushort4*)&xws1b[gr * F1 + c0] = o;
        }
    }
}

// ---- gather1 + gemm2 fused. Round-15: full software pipeline.
// Round-14 post-mortem: persistent blocks fixed residency (Occ 55%) but
// VALUBusy stayed ~33% — the per-node serial chain rowptr->csr->rows was
// still cold every node (only rowptr/deg was prefetched). Now the issue
// phase launches next node's meta + csr + first 2 row-chunks (16 edges),
// PLUS current node's chunk-2 (edges 16..23, P(deg>16)~43%), all hidden
// under current node's compute. Serial tail only for deg>24 (~2%). ----
__global__ __launch_bounds__(256, 8) void gather1f(const int* __restrict__ csr,
                                                   const int* __restrict__ rowptr,
                                                   const int* __restrict__ deg,
                                                   const float* __restrict__ dinv,
                                                   const unsigned short* __restrict__ xb,
                                                   const float* __restrict__ b1,
                                                   const float* __restrict__ W2,
                                                   unsigned short* __restrict__ xws2b,
                                                   int N, int kh) {
    __shared__ float sW2[F1][F2];    // 8 KB
    __shared__ float h1s[4][F1];     // 1 KB
    int tid = threadIdx.x;
    for (int i = tid; i < (F1 * F2) / 4; i += 256)
        ((float4*)&sW2[0][0])[i] = ((const float4*)W2)[i];
    __syncthreads();

    int wv = tid >> 6, lane = tid & 63;
    int grp = lane >> 3;           // edge slot 0..7
    int fb = (lane & 7) << 3;      // feature base 0..56 (8 features/lane)
    int c = lane & 31, half = lane >> 5;
    int k0 = half * 32;
    int stride = gridDim.x * 4;

    int node = blockIdx.x * 4 + wv;

    // ---- prologue: node's meta + first two chunks ----
    int start = 0, cnt = 0;
    float dd = 0.f;
    bool p0 = false, p1 = false;
    uint4 v0, v1;
    if (node < N) {
        start = rfl(rowptr[node]); cnt = rfl(deg[node]);
        dd = dinv[node];
        int e0 = grp, e1 = grp + 8;
        p0 = e0 < cnt; p1 = e1 < cnt;
        int s0 = 0, s1 = 0;
        if (p0) s0 = csr[start + e0];
        if (p1) s1 = csr[start + e1];
        if (p0) v0 = *(const uint4*)(xb + (size_t)s0 * F1 + fb);
        if (p1) v1 = *(const uint4*)(xb + (size_t)s1 * F1 + fb);
    }

    while (node < N) {
        // ---- issue phase: next node's meta + chunks 0,1; current chunk 2 ----
        int nnode = node + stride;
        int nstart = 0, ncnt = 0;
        float ndd = 0.f;
        bool np0 = false, np1 = false;
        uint4 nv0, nv1;
        if (nnode < N) {
            nstart = rfl(rowptr[nnode]); ncnt = rfl(deg[nnode]);
            ndd = dinv[nnode];
            int e0 = grp, e1 = grp + 8;
            np0 = e0 < ncnt; np1 = e1 < ncnt;
            int ns0 = 0, ns1 = 0;
            if (np0) ns0 = csr[nstart + e0];
            if (np1) ns1 = csr[nstart + e1];
            if (np0) nv0 = *(const uint4*)(xb + (size_t)ns0 * F1 + fb);
            if (np1) nv1 = *(const uint4*)(xb + (size_t)ns1 * F1 + fb);
        }
        // current node's chunk 2 (edges 16..23) — common case P~43%
        bool p2 = (16 + grp) < cnt;
        uint4 v2;
        if (p2) {
            int s2 = csr[start + 16 + grp];
            v2 = *(const uint4*)(xb + (size_t)s2 * F1 + fb);
        }
        // self row (needed late; issued here so latency hides under acc)
        uint4 vs = *(const uint4*)(xb + (size_t)node * F1 + fb);

        // ---- compute phase ----
        float acc[8] = {};
        if (p0) acc8(acc, v0);
        if (p1) acc8(acc, v1);
        if (p2) acc8(acc, v2);
        // rare serial tail: deg > 24 (~2% of nodes)
        for (int j = 24; j < cnt; j += 8) {
            int e = j + grp;
            if (e < cnt) {
                int s = csr[start + e];
                uint4 w = *(const uint4*)(xb + (size_t)s * F1 + fb);
                acc8(acc, w);
            }
        }
        if (grp == 0) acc8(acc, vs);   // self-loop, exactly once

        #pragma unroll
        for (int off = 8; off < 64; off <<= 1)
            #pragma unroll
            for (int i = 0; i < 8; ++i)
                acc[i] += __shfl_xor(acc[i], off, 64);

        if (lane < 8) {   // lanes 0..7 cover all 64 features (8 each)
            float4 bA = *(const float4*)&b1[fb];
            float4 bB = *(const float4*)&b1[fb + 4];
            float4 p, q;
            p.x = fmaxf(dd * acc[0] + bA.x, 0.f);
            p.y = fmaxf(dd * acc[1] + bA.y, 0.f);
            p.z = fmaxf(dd * acc[2] + bA.z, 0.f);
            p.w = fmaxf(dd * acc[3] + bA.w, 0.f);
            q.x = fmaxf(dd * acc[4] + bB.x, 0.f);
            q.y = fmaxf(dd * acc[5] + bB.y, 0.f);
            q.z = fmaxf(dd * acc[6] + bB.z, 0.f);
            q.w = fmaxf(dd * acc[7] + bB.w, 0.f);
            *(float4*)&h1s[wv][fb] = p;
            *(float4*)&h1s[wv][fb + 4] = q;
        }

        // GEMV: h1[64] @ W2[64][32], split k across wave halves
        float d0 = 0.f, d1 = 0.f, d2 = 0.f, d3 = 0.f;
        for (int k = 0; k < kh; k += 4) {
            d0 += h1s[wv][k0 + k]     * sW2[k0 + k][c];
            d1 += h1s[wv][k0 + k + 1] * sW2[k0 + k + 1][c];
            d2 += h1s[wv][k0 + k + 2] * sW2[k0 + k + 2][c];
            d3 += h1s[wv][k0 + k + 3] * sW2[k0 + k + 3][c];
        }
        float dot = (d0 + d1) + (d2 + d3);
        dot += __shfl_down(dot, 32, 64);
        if (half == 0) xws2b[node * F2 + c] = f2b(dot * dd);

        // rotate pipeline state
        node = nnode; start = nstart; cnt = ncnt; dd = ndd;
        p0 = np0; p1 = np1; v0 = nv0; v1 = nv1;
    }
}

// ---- gather2 + gemm3 fused. Same pipeline: next node's meta + csr + 2 chunks
// (32 edges, P(deg>32)~0.01%) issued under current compute. `out` written
// with NON-TEMPORAL stores: write-once — avoid L2 RFO. ----
__global__ __launch_bounds__(256, 8) void gather2f(const int* __restrict__ csr,
                                                   const int* __restrict__ rowptr,
                                                   const int* __restrict__ deg,
                                                   const float* __restrict__ dinv,
                                                   const unsigned short* __restrict__ xb,
                                                   const float* __restrict__ b2,
                                                   const float* __restrict__ Wl,
                                                   const float* __restrict__ bl,
                                                   float* __restrict__ out, int N, int kh) {
    __shared__ float sWl[F2][F0];    // 16 KB
    __shared__ float h2s[4][F2];     // 512 B
    int tid = threadIdx.x;
    for (int i = tid; i < (F2 * F0) / 4; i += 256)
        ((float4*)&sWl[0][0])[i] = ((const float4*)Wl)[i];
    __syncthreads();

    int wv = tid >> 6, lane = tid & 63;
    int grp = lane >> 2;           // edge slot 0..15
    int fb = (lane & 3) << 3;      // feature base 0,8,16,24 (8 features/lane)
    int stride = gridDim.x * 4;

    int node = blockIdx.x * 4 + wv;

    int start = 0, cnt = 0;
    float dd = 0.f;
    bool p0 = false, p1 = false;
    uint4 v0, v1;
    if (node < N) {
        start = rfl(rowptr[node]); cnt = rfl(deg[node]);
        dd = dinv[node];
        int e0 = grp, e1 = grp + 16;
        p0 = e0 < cnt; p1 = e1 < cnt;
        int s0 = 0, s1 = 0;
        if (p0) s0 = csr[start + e0];
        if (p1) s1 = csr[start + e1];
        if (p0) v0 = *(const uint4*)(xb + (size_t)s0 * F2 + fb);
        if (p1) v1 = *(const uint4*)(xb + (size_t)s1 * F2 + fb);
    }

    while (node < N) {
        int nnode = node + stride;
        int nstart = 0, ncnt = 0;
        float ndd = 0.f;
        bool np0 = false, np1 = false;
        uint4 nv0, nv1;
        if (nnode < N) {
            nstart = rfl(rowptr[nnode]); ncnt = rfl(deg[nnode]);
            ndd = dinv[nnode];
            int e0 = grp, e1 = grp + 16;
            np0 = e0 < ncnt; np1 = e1 < ncnt;
            int ns0 = 0, ns1 = 0;
            if (np0) ns0 = csr[nstart + e0];
            if (np1) ns1 = csr[nstart + e1];
            if (np0) nv0 = *(const uint4*)(xb + (size_t)ns0 * F2 + fb);
            if (np1) nv1 = *(const uint4*)(xb + (size_t)ns1 * F2 + fb);
        }
        uint4 vs = *(const uint4*)(xb + (size_t)node * F2 + fb);  // self row

        float acc[8] = {};
        if (p0) acc8(acc, v0);
        if (p1) acc8(acc, v1);
        // ultra-rare serial tail: deg > 32
        for (int j = 32; j < cnt; j += 16) {
            int e = j + grp;
            if (e < cnt) {
                int s = csr[start + e];
                uint4 w = *(const uint4*)(xb + (size_t)s * F2 + fb);
                acc8(acc, w);
            }
        }
        if (grp == 0) acc8(acc, vs);   // self-loop

        #pragma unroll
        for (int off = 4; off < 64; off <<= 1)
            #pragma unroll
            for (int i = 0; i < 8; ++i)
                acc[i] += __shfl_xor(acc[i], off, 64);

        if (lane < 4) {   // lanes 0..3 cover all 32 features (8 each)
            float4 bA = *(const float4*)&b2[fb];
            float4 bB = *(const float4*)&b2[fb + 4];
            float4 p, q;
            p.x = fmaxf(dd * acc[0] + bA.x, 0.f);
            p.y = fmaxf(dd * acc[1] + bA.y, 0.f);
            p.z = fmaxf(dd * acc[2] + bA.z, 0.f);
            p.w = fmaxf(dd * acc[3] + bA.w, 0.f);
            q.x = fmaxf(dd * acc[4] + bB.x, 0.f);
            q.y = fmaxf(dd * acc[5] + bB.y, 0.f);
            q.z = fmaxf(dd * acc[6] + bB.z, 0.f);
            q.w = fmaxf(dd * acc[7] + bB.w, 0.f);
            *(float4*)&h2s[wv][fb] = p;
            *(float4*)&h2s[wv][fb + 4] = q;
        }

        // final GEMV: h2[32] @ Wl[32][128] + bl
        float e0 = 0.f, e1 = 0.f, f0 = 0.f, f1 = 0.f;
        for (int k = 0; k < kh; k += 2) {
            float hk0 = h2s[wv][k], hk1 = h2s[wv][k + 1];
            e0 += hk0 * sWl[k][lane];
            e1 += hk1 * sWl[k + 1][lane];
            f0 += hk0 * sWl[k][lane + 64];
            f1 += hk1 * sWl[k + 1][lane + 64];
        }
        size_t ob = (size_t)node * F0;
        __builtin_nontemporal_store((e0 + e1) + bl[lane],      &out[ob + lane]);
        __builtin_nontemporal_store((f0 + f1) + bl[lane + 64], &out[ob + lane + 64]);

        node = nnode; start = nstart; cnt = ncnt; dd = ndd;
        p0 = np0; p1 = np1; v0 = nv0; v1 = nv1;
    }
}

extern "C" void kernel_launch(void* const* d_in, const int* in_sizes, int n_in,
                              void* d_out, int out_size, void* d_ws, size_t ws_size,
                              hipStream_t stream) {
    const float* x  = (const float*)d_in[0];
    const int*   ei = (const int*)d_in[1];
    const float* W1 = (const float*)d_in[2];
    const float* b1 = (const float*)d_in[3];
    const float* W2 = (const float*)d_in[4];
    const float* b2 = (const float*)d_in[5];
    const float* Wl = (const float*)d_in[6];
    const float* bl = (const float*)d_in[7];
    float* out = (float*)d_out;

    const int N = in_sizes[0] / F0;   // 50000
    const int E = in_sizes[1] / 2;    // 800000
    const int* src = ei;
    const int* dst = ei + E;
    const int NB = (N + 255) / 256;   // 196

    char* ws = (char*)d_ws;
    size_t off = 0;
    auto alloc = [&](size_t bytes) {
        void* p = ws + off;
        off += (bytes + 255) & ~(size_t)255;
        return p;
    };
    int*            deg    = (int*)alloc((size_t)N * 4);
    float*          dinv   = (float*)alloc((size_t)N * 4);
    int*            rowptr = (int*)alloc((size_t)N * 4);
    int*            cursor = (int*)alloc((size_t)N * 4);
    int*            bsum   = (int*)alloc((size_t)NB * 4);
    int*            boff   = (int*)alloc((size_t)NB * 4);
    int*            csr    = (int*)alloc((size_t)E * 4);
    unsigned short* xws1b  = (unsigned short*)alloc((size_t)N * F1 * 2);
    unsigned short* xws2b  = (unsigned short*)alloc((size_t)N * F2 * 2);

    hipMemsetAsync(deg, 0, (size_t)N * 4, stream);
    deg_count<<<(E + 255) / 256, 256, 0, stream>>>(dst, deg, E);
    scan1<<<NB, 256, 0, stream>>>(deg, dinv, rowptr, bsum, N);
    scan2<<<1, 256, 0, stream>>>(bsum, boff, NB);
    scan3<<<NB, 256, 0, stream>>>(rowptr, boff, cursor, N);
    bucket8<<<1024, 256, 0, stream>>>(src, dst, cursor, csr, E, N);

    gemm1<<<(N + 63) / 64, 256, 0, stream>>>(x, W1, dinv, xws1b, N, 64);
    gather1f<<<2048, 256, 0, stream>>>(csr, rowptr, deg, dinv, xws1b, b1, W2, xws2b, N, 32);
    gather2f<<<2048, 256, 0, stream>>>(csr, rowptr, deg, dinv, xws2b, b2, Wl, bl, out, N, 32);
}

// Round 4
// 252.083 us; speedup vs baseline: 1.0488x; 1.0488x over previous
//
#include <hip/hip_runtime.h>

#define F0 128
#define F1 64
#define F2 32

__device__ __forceinline__ int rfl(int v) { return __builtin_amdgcn_readfirstlane(v); }

// bf16 helpers (RNE)
__device__ __forceinline__ unsigned short f2b(float f) {
    unsigned u = __float_as_uint(f);
    return (unsigned short)((u + 0x7fffu + ((u >> 16) & 1u)) >> 16);
}
__device__ __forceinline__ float b2f(unsigned short u) {
    return __uint_as_float(((unsigned)u) << 16);
}

// accumulate 8 bf16 (packed in a uint4) into 8 float accumulators
__device__ __forceinline__ void acc8(float* a, uint4 v) {
    a[0] += __uint_as_float(v.x << 16);
    a[1] += __uint_as_float(v.x & 0xffff0000u);
    a[2] += __uint_as_float(v.y << 16);
    a[3] += __uint_as_float(v.y & 0xffff0000u);
    a[4] += __uint_as_float(v.z << 16);
    a[5] += __uint_as_float(v.z & 0xffff0000u);
    a[6] += __uint_as_float(v.w << 16);
    a[7] += __uint_as_float(v.w & 0xffff0000u);
}

// ---------------- degree ----------------
__global__ void deg_count(const int* __restrict__ dst, int* __restrict__ deg, int E) {
    int e = blockIdx.x * blockDim.x + threadIdx.x;
    if (e < E) atomicAdd(&deg[dst[e]], 1);
}

// ---------------- scan (3 kernels; round-9 post-mortem: single-block fused scan
// was 135 us latency-bound on one CU — multi-block version is ~5 us) ----------------
__global__ void scan1(const int* __restrict__ deg, float* __restrict__ dinv,
                      int* __restrict__ rowptr, int* __restrict__ bsum, int N) {
    __shared__ int s[256];
    int i = blockIdx.x * 256 + threadIdx.x;
    int v = (i < N) ? deg[i] : 0;
    if (i < N) dinv[i] = rsqrtf((float)(v + 1));  // +1 self-loop
    s[threadIdx.x] = v;
    __syncthreads();
    for (int off = 1; off < 256; off <<= 1) {
        int t = 0;
        if (threadIdx.x >= off) t = s[threadIdx.x - off];
        __syncthreads();
        if (threadIdx.x >= off) s[threadIdx.x] += t;
        __syncthreads();
    }
    if (i < N) rowptr[i] = s[threadIdx.x] - v;
    if (threadIdx.x == 255) bsum[blockIdx.x] = s[255];
}

__global__ void scan2(int* __restrict__ bsum, int* __restrict__ boff, int nb) {
    __shared__ int s[256];
    int v = (threadIdx.x < nb) ? bsum[threadIdx.x] : 0;
    s[threadIdx.x] = v;
    __syncthreads();
    for (int off = 1; off < 256; off <<= 1) {
        int t = 0;
        if (threadIdx.x >= off) t = s[threadIdx.x - off];
        __syncthreads();
        if (threadIdx.x >= off) s[threadIdx.x] += t;
        __syncthreads();
    }
    if (threadIdx.x < nb) boff[threadIdx.x] = s[threadIdx.x] - v;
}

__global__ void scan3(int* __restrict__ rowptr, const int* __restrict__ boff,
                      int* __restrict__ cursor, int N) {
    int i = blockIdx.x * 256 + threadIdx.x;
    if (i < N) {
        int v = rowptr[i] + boff[blockIdx.x];
        rowptr[i] = v;
        cursor[i] = v;
    }
}

// ---------------- bucket, XCD-pinned by dst partition (blockIdx&7) ----------------
__global__ __launch_bounds__(256) void bucket8(const int* __restrict__ src,
                                               const int* __restrict__ dst,
                                               int* __restrict__ cursor,
                                               int* __restrict__ csr, int E, int N) {
    int part = blockIdx.x & 7;
    int g = blockIdx.x >> 3;
    int G = gridDim.x >> 3;
    int plo = (int)(((long long)N * part) >> 3);
    int phi = (int)(((long long)N * (part + 1)) >> 3);
    for (int e = g * 256 + threadIdx.x; e < E; e += G * 256) {
        int d = dst[e];
        if (d >= plo && d < phi) {
            int pos = atomicAdd(&cursor[d], 1);
            csr[pos] = src[e];
        }
    }
}

// ---------------- GEMM1: xws1b = bf16((x @ W1) * dinv[row])   [N,128]x[128,64] -------
// k-loop bound `kb` is a RUNTIME arg so the compiler cannot fully unroll
// (round-5 post-mortem: full unroll -> 256 VGPR -> 750 MB scratch spill).
__global__ __launch_bounds__(256) void gemm1(const float* __restrict__ x,
                                             const float* __restrict__ W1,
                                             const float* __restrict__ dinv,
                                             unsigned short* __restrict__ xws1b,
                                             int N, int kb) {
    __shared__ float sx[64][132];
    __shared__ float sW[64][64];
    int tid = threadIdx.x;
    int row0 = blockIdx.x * 64;

    for (int i = tid; i < 2048; i += 256) {
        int r = i >> 5, kq = i & 31;
        int gr = row0 + r;
        float4 v = make_float4(0.f, 0.f, 0.f, 0.f);
        if (gr < N) v = ((const float4*)(x + (size_t)gr * F0))[kq];
        *(float4*)(&sx[r][kq << 2]) = v;
    }

    int tx = tid & 15, ty = tid >> 4;
    int c0 = tx * 4, r0 = ty * 4;
    float acc[4][4] = {};

    const float4* W4 = (const float4*)W1;
    float4* sW4 = (float4*)(&sW[0][0]);

    for (int p = 0; p < 2; ++p) {
        if (p) __syncthreads();
        for (int i = tid; i < 1024; i += 256) sW4[i] = W4[p * 1024 + i];
        __syncthreads();
        int kbase = p * 64;
        for (int k = 0; k < kb; k += 4) {
            float a[4][4], b[4][4];
            #pragma unroll
            for (int rr = 0; rr < 4; ++rr)
                *(float4*)&a[rr][0] = *(const float4*)&sx[r0 + rr][kbase + k];
            #pragma unroll
            for (int j = 0; j < 4; ++j)
                *(float4*)&b[j][0] = *(const float4*)&sW[k + j][c0];
            #pragma unroll
            for (int j = 0; j < 4; ++j)
                #pragma unroll
                for (int rr = 0; rr < 4; ++rr)
                    #pragma unroll
                    for (int cc = 0; cc < 4; ++cc)
                        acc[rr][cc] += a[rr][j] * b[j][cc];
        }
    }

    #pragma unroll
    for (int rr = 0; rr < 4; ++rr) {
        int gr = row0 + r0 + rr;
        if (gr < N) {
            float s = dinv[gr];
            ushort4 o;
            o.x = f2b(acc[rr][0] * s); o.y = f2b(acc[rr][1] * s);
            o.z = f2b(acc[rr][2] * s); o.w = f2b(acc[rr][3] * s);
            *(ushort4*)&xws1b[gr * F1 + c0] = o;
        }
    }
}

// ---- gather1 + gemm2 fused. Round-16: kill the LDS pipe bottleneck.
// Round-15 post-mortem: VALUBusy ~33% with Occ 63% and HBM 12% — the per-CU
// LDS pipe was saturated: ~130 LDS instrs/node (32 bpermute reduce + ~96
// scalar ds_read GEMV) x 195 nodes/CU x ~5cy ~= 50 us = measured time.
// Fix: (a) reduce-scatter (7 shuffles, not 24) — each lane ends owning ONE
// feature f(lane), applies dd/bias/relu in-register, 1 scatter ds_write;
// (b) W2 column slice lives in 32 VGPRs (loaded once per persistent block),
// GEMV = 8 broadcast ds_read_b128 + 32 v_fma, fully unrolled. ----
__global__ __launch_bounds__(256, 5) void gather1f(const int* __restrict__ csr,
                                                   const int* __restrict__ rowptr,
                                                   const int* __restrict__ deg,
                                                   const float* __restrict__ dinv,
                                                   const unsigned short* __restrict__ xb,
                                                   const float* __restrict__ b1,
                                                   const float* __restrict__ W2,
                                                   unsigned short* __restrict__ xws2b,
                                                   int N) {
    __shared__ float h1s[4][F1];     // per-wave staging, 1 KB
    int tid = threadIdx.x;
    int wv = tid >> 6, lane = tid & 63;
    int grp = lane >> 3;             // edge slot 0..7
    int fb = (lane & 7) << 3;        // feature base (8 features/lane in gather)
    int b3 = (lane >> 3) & 1, b4 = (lane >> 4) & 1, b5 = lane >> 5;
    int f = fb + b3 * 4 + b4 * 2 + b5;   // feature owned after reduce-scatter (bijection)
    float breg = b1[f];
    int c = lane & 31, half = b5;
    int k0 = half * 32;
    // W2 column slice in registers: wreg[j] = W2[k0+j][c]  (once per block)
    float wreg[32];
    #pragma unroll
    for (int j = 0; j < 32; ++j) wreg[j] = W2[(k0 + j) * F2 + c];

    int stride = gridDim.x * 4;
    for (int node = blockIdx.x * 4 + wv; node < N; node += stride) {
        int start = rfl(rowptr[node]);
        int cnt = rfl(deg[node]);
        float dd = dinv[node];

        float acc[8] = {};
        uint4 vs = *(const uint4*)(xb + (size_t)node * F1 + fb);  // self row
        for (int j = 0; j < cnt; j += 16) {
            int e0 = j + grp, e1 = e0 + 8;
            bool p0 = e0 < cnt, p1 = e1 < cnt;
            int s0 = 0, s1 = 0;
            if (p0) s0 = csr[start + e0];
            if (p1) s1 = csr[start + e1];
            uint4 v0, v1;
            if (p0) v0 = *(const uint4*)(xb + (size_t)s0 * F1 + fb);
            if (p1) v1 = *(const uint4*)(xb + (size_t)s1 * F1 + fb);
            if (p0) acc8(acc, v0);
            if (p1) acc8(acc, v1);
        }
        if (grp == 0) acc8(acc, vs);   // self-loop, exactly once

        // reduce-scatter over grp bits: xor8 (4 shfl), xor16 (2), xor32 (1)
        float L[4];
        #pragma unroll
        for (int i = 0; i < 4; ++i) {
            float s = b3 ? acc[i] : acc[i + 4];
            float r = __shfl_xor(s, 8, 64);
            L[i] = (b3 ? acc[i + 4] : acc[i]) + r;
        }
        float M[2];
        #pragma unroll
        for (int i = 0; i < 2; ++i) {
            float s = b4 ? L[i] : L[i + 2];
            float r = __shfl_xor(s, 16, 64);
            M[i] = (b4 ? L[i + 2] : L[i]) + r;
        }
        float sx_ = b5 ? M[0] : M[1];
        float rx = __shfl_xor(sx_, 32, 64);
        float hv = (b5 ? M[1] : M[0]) + rx;

        hv = fmaxf(dd * hv + breg, 0.f);   // bias+relu in-register
        h1s[wv][f] = hv;                   // 1 scatter write (bijective -> conflict-free)

        // GEMV: dot(h1[k0..k0+31], wreg); k split across wave halves
        float dot = 0.f;
        #pragma unroll
        for (int t = 0; t < 8; ++t) {
            float4 hb = *(const float4*)&h1s[wv][k0 + t * 4];
            dot += hb.x * wreg[t * 4] + hb.y * wreg[t * 4 + 1]
                 + hb.z * wreg[t * 4 + 2] + hb.w * wreg[t * 4 + 3];
        }
        dot += __shfl_xor(dot, 32, 64);
        if (half == 0) xws2b[node * F2 + c] = f2b(dot * dd);
    }
}

// ---- gather2 + gemm3 fused. Same LDS-diet rework: reduce-scatter (8 shfl),
// Wl 2-column slice in 64 VGPRs, GEMV = 8 broadcast b128 reads + 64 fma.
// `out` written with NON-TEMPORAL stores (write-once, avoid L2 RFO). ----
__global__ __launch_bounds__(256, 4) void gather2f(const int* __restrict__ csr,
                                                   const int* __restrict__ rowptr,
                                                   const int* __restrict__ deg,
                                                   const float* __restrict__ dinv,
                                                   const unsigned short* __restrict__ xb,
                                                   const float* __restrict__ b2,
                                                   const float* __restrict__ Wl,
                                                   const float* __restrict__ bl,
                                                   float* __restrict__ out, int N) {
    __shared__ float h2s[4][F2];     // per-wave staging, 512 B
    int tid = threadIdx.x;
    int wv = tid >> 6, lane = tid & 63;
    int grp = lane >> 2;             // edge slot 0..15
    int fb = (lane & 3) << 3;        // feature base (8 features/lane in gather)
    int bb2 = (lane >> 2) & 1, b3 = (lane >> 3) & 1, b4 = (lane >> 4) & 1, b5 = lane >> 5;
    int f = fb + bb2 * 4 + b3 * 2 + b4;  // feature owned after reduce-scatter (dup over b5)
    float breg = b2[f];
    float blA = bl[lane], blB = bl[lane + 64];
    // Wl 2-column slice in registers: wregA[j]=Wl[j][lane], wregB[j]=Wl[j][lane+64]
    float wregA[32], wregB[32];
    #pragma unroll
    for (int j = 0; j < 32; ++j) {
        wregA[j] = Wl[j * F0 + lane];
        wregB[j] = Wl[j * F0 + lane + 64];
    }

    int stride = gridDim.x * 4;
    for (int node = blockIdx.x * 4 + wv; node < N; node += stride) {
        int start = rfl(rowptr[node]);
        int cnt = rfl(deg[node]);
        float dd = dinv[node];

        float acc[8] = {};
        uint4 vs = *(const uint4*)(xb + (size_t)node * F2 + fb);  // self row
        for (int j = 0; j < cnt; j += 32) {
            int e0 = j + grp, e1 = e0 + 16;
            bool p0 = e0 < cnt, p1 = e1 < cnt;
            int s0 = 0, s1 = 0;
            if (p0) s0 = csr[start + e0];
            if (p1) s1 = csr[start + e1];
            uint4 v0, v1;
            if (p0) v0 = *(const uint4*)(xb + (size_t)s0 * F2 + fb);
            if (p1) v1 = *(const uint4*)(xb + (size_t)s1 * F2 + fb);
            if (p0) acc8(acc, v0);
            if (p1) acc8(acc, v1);
        }
        if (grp == 0) acc8(acc, vs);   // self-loop

        // reduce-scatter over grp bits: xor4 (4), xor8 (2), xor16 (1), xor32 (1)
        float L[4];
        #pragma unroll
        for (int i = 0; i < 4; ++i) {
            float s = bb2 ? acc[i] : acc[i + 4];
            float r = __shfl_xor(s, 4, 64);
            L[i] = (bb2 ? acc[i + 4] : acc[i]) + r;
        }
        float M[2];
        #pragma unroll
        for (int i = 0; i < 2; ++i) {
            float s = b3 ? L[i] : L[i + 2];
            float r = __shfl_xor(s, 8, 64);
            M[i] = (b3 ? L[i + 2] : L[i]) + r;
        }
        float sx_ = b4 ? M[0] : M[1];
        float rx = __shfl_xor(sx_, 16, 64);
        float hv = (b4 ? M[1] : M[0]) + rx;
        hv += __shfl_xor(hv, 32, 64);      // both halves now hold full sum for f

        hv = fmaxf(dd * hv + breg, 0.f);
        if (!b5) h2s[wv][f] = hv;          // 32 distinct banks -> conflict-free

        // final GEMV: out[c] = dot(h2[0..31], Wl[:,c]) + bl, c = lane and lane+64
        float dA = 0.f, dB = 0.f;
        #pragma unroll
        for (int t = 0; t < 8; ++t) {
            float4 hb = *(const float4*)&h2s[wv][t * 4];
            dA += hb.x * wregA[t * 4] + hb.y * wregA[t * 4 + 1]
                + hb.z * wregA[t * 4 + 2] + hb.w * wregA[t * 4 + 3];
            dB += hb.x * wregB[t * 4] + hb.y * wregB[t * 4 + 1]
                + hb.z * wregB[t * 4 + 2] + hb.w * wregB[t * 4 + 3];
        }
        size_t ob = (size_t)node * F0;
        __builtin_nontemporal_store(dA + blA, &out[ob + lane]);
        __builtin_nontemporal_store(dB + blB, &out[ob + lane + 64]);
    }
}

extern "C" void kernel_launch(void* const* d_in, const int* in_sizes, int n_in,
                              void* d_out, int out_size, void* d_ws, size_t ws_size,
                              hipStream_t stream) {
    const float* x  = (const float*)d_in[0];
    const int*   ei = (const int*)d_in[1];
    const float* W1 = (const float*)d_in[2];
    const float* b1 = (const float*)d_in[3];
    const float* W2 = (const float*)d_in[4];
    const float* b2 = (const float*)d_in[5];
    const float* Wl = (const float*)d_in[6];
    const float* bl = (const float*)d_in[7];
    float* out = (float*)d_out;

    const int N = in_sizes[0] / F0;   // 50000
    const int E = in_sizes[1] / 2;    // 800000
    const int* src = ei;
    const int* dst = ei + E;
    const int NB = (N + 255) / 256;   // 196

    char* ws = (char*)d_ws;
    size_t off = 0;
    auto alloc = [&](size_t bytes) {
        void* p = ws + off;
        off += (bytes + 255) & ~(size_t)255;
        return p;
    };
    int*            deg    = (int*)alloc((size_t)N * 4);
    float*          dinv   = (float*)alloc((size_t)N * 4);
    int*            rowptr = (int*)alloc((size_t)N * 4);
    int*            cursor = (int*)alloc((size_t)N * 4);
    int*            bsum   = (int*)alloc((size_t)NB * 4);
    int*            boff   = (int*)alloc((size_t)NB * 4);
    int*            csr    = (int*)alloc((size_t)E * 4);
    unsigned short* xws1b  = (unsigned short*)alloc((size_t)N * F1 * 2);
    unsigned short* xws2b  = (unsigned short*)alloc((size_t)N * F2 * 2);

    hipMemsetAsync(deg, 0, (size_t)N * 4, stream);
    deg_count<<<(E + 255) / 256, 256, 0, stream>>>(dst, deg, E);
    scan1<<<NB, 256, 0, stream>>>(deg, dinv, rowptr, bsum, N);
    scan2<<<1, 256, 0, stream>>>(bsum, boff, NB);
    scan3<<<NB, 256, 0, stream>>>(rowptr, boff, cursor, N);
    bucket8<<<1024, 256, 0, stream>>>(src, dst, cursor, csr, E, N);

    gemm1<<<(N + 63) / 64, 256, 0, stream>>>(x, W1, dinv, xws1b, N, 64);
    gather1f<<<2048, 256, 0, stream>>>(csr, rowptr, deg, dinv, xws1b, b1, W2, xws2b, N);
    gather2f<<<2048, 256, 0, stream>>>(csr, rowptr, deg, dinv, xws2b, b2, Wl, bl, out, N);
}

// Round 5
// 244.973 us; speedup vs baseline: 1.0793x; 1.0290x over previous
//
#include <hip/hip_runtime.h>

#define F0 128
#define F1 64
#define F2 32

__device__ __forceinline__ int rfl(int v) { return __builtin_amdgcn_readfirstlane(v); }

// bf16 helpers (RNE)
__device__ __forceinline__ unsigned short f2b(float f) {
    unsigned u = __float_as_uint(f);
    return (unsigned short)((u + 0x7fffu + ((u >> 16) & 1u)) >> 16);
}
__device__ __forceinline__ float b2f(unsigned short u) {
    return __uint_as_float(((unsigned)u) << 16);
}

// accumulate 8 bf16 (packed in a uint4) into 8 float accumulators
__device__ __forceinline__ void acc8(float* a, uint4 v) {
    a[0] += __uint_as_float(v.x << 16);
    a[1] += __uint_as_float(v.x & 0xffff0000u);
    a[2] += __uint_as_float(v.y << 16);
    a[3] += __uint_as_float(v.y & 0xffff0000u);
    a[4] += __uint_as_float(v.z << 16);
    a[5] += __uint_as_float(v.z & 0xffff0000u);
    a[6] += __uint_as_float(v.w << 16);
    a[7] += __uint_as_float(v.w & 0xffff0000u);
}

// ---------------- degree ----------------
__global__ void deg_count(const int* __restrict__ dst, int* __restrict__ deg, int E) {
    int e = blockIdx.x * blockDim.x + threadIdx.x;
    if (e < E) atomicAdd(&deg[dst[e]], 1);
}

// ---------------- scan (3 kernels; round-9 post-mortem: single-block fused scan
// was 135 us latency-bound on one CU — multi-block version is ~5 us) ----------------
__global__ void scan1(const int* __restrict__ deg, float* __restrict__ dinv,
                      int* __restrict__ rowptr, int* __restrict__ bsum, int N) {
    __shared__ int s[256];
    int i = blockIdx.x * 256 + threadIdx.x;
    int v = (i < N) ? deg[i] : 0;
    if (i < N) dinv[i] = rsqrtf((float)(v + 1));  // +1 self-loop
    s[threadIdx.x] = v;
    __syncthreads();
    for (int off = 1; off < 256; off <<= 1) {
        int t = 0;
        if (threadIdx.x >= off) t = s[threadIdx.x - off];
        __syncthreads();
        if (threadIdx.x >= off) s[threadIdx.x] += t;
        __syncthreads();
    }
    if (i < N) rowptr[i] = s[threadIdx.x] - v;
    if (threadIdx.x == 255) bsum[blockIdx.x] = s[255];
}

__global__ void scan2(int* __restrict__ bsum, int* __restrict__ boff, int nb) {
    __shared__ int s[256];
    int v = (threadIdx.x < nb) ? bsum[threadIdx.x] : 0;
    s[threadIdx.x] = v;
    __syncthreads();
    for (int off = 1; off < 256; off <<= 1) {
        int t = 0;
        if (threadIdx.x >= off) t = s[threadIdx.x - off];
        __syncthreads();
        if (threadIdx.x >= off) s[threadIdx.x] += t;
        __syncthreads();
    }
    if (threadIdx.x < nb) boff[threadIdx.x] = s[threadIdx.x] - v;
}

__global__ void scan3(int* __restrict__ rowptr, const int* __restrict__ boff,
                      int* __restrict__ cursor, int N) {
    int i = blockIdx.x * 256 + threadIdx.x;
    if (i < N) {
        int v = rowptr[i] + boff[blockIdx.x];
        rowptr[i] = v;
        cursor[i] = v;
    }
}

// ---------------- bucket, XCD-pinned by dst partition (blockIdx&7) ----------------
__global__ __launch_bounds__(256) void bucket8(const int* __restrict__ src,
                                               const int* __restrict__ dst,
                                               int* __restrict__ cursor,
                                               int* __restrict__ csr, int E, int N) {
    int part = blockIdx.x & 7;
    int g = blockIdx.x >> 3;
    int G = gridDim.x >> 3;
    int plo = (int)(((long long)N * part) >> 3);
    int phi = (int)(((long long)N * (part + 1)) >> 3);
    for (int e = g * 256 + threadIdx.x; e < E; e += G * 256) {
        int d = dst[e];
        if (d >= plo && d < phi) {
            int pos = atomicAdd(&cursor[d], 1);
            csr[pos] = src[e];
        }
    }
}

// ---------------- GEMM1: xws1b = bf16((x @ W1) * dinv[row])   [N,128]x[128,64] -------
// k-loop bound `kb` is a RUNTIME arg so the compiler cannot fully unroll
// (round-5 post-mortem: full unroll -> 256 VGPR -> 750 MB scratch spill).
__global__ __launch_bounds__(256) void gemm1(const float* __restrict__ x,
                                             const float* __restrict__ W1,
                                             const float* __restrict__ dinv,
                                             unsigned short* __restrict__ xws1b,
                                             int N, int kb) {
    __shared__ float sx[64][132];
    __shared__ float sW[64][64];
    int tid = threadIdx.x;
    int row0 = blockIdx.x * 64;

    for (int i = tid; i < 2048; i += 256) {
        int r = i >> 5, kq = i & 31;
        int gr = row0 + r;
        float4 v = make_float4(0.f, 0.f, 0.f, 0.f);
        if (gr < N) v = ((const float4*)(x + (size_t)gr * F0))[kq];
        *(float4*)(&sx[r][kq << 2]) = v;
    }

    int tx = tid & 15, ty = tid >> 4;
    int c0 = tx * 4, r0 = ty * 4;
    float acc[4][4] = {};

    const float4* W4 = (const float4*)W1;
    float4* sW4 = (float4*)(&sW[0][0]);

    for (int p = 0; p < 2; ++p) {
        if (p) __syncthreads();
        for (int i = tid; i < 1024; i += 256) sW4[i] = W4[p * 1024 + i];
        __syncthreads();
        int kbase = p * 64;
        for (int k = 0; k < kb; k += 4) {
            float a[4][4], b[4][4];
            #pragma unroll
            for (int rr = 0; rr < 4; ++rr)
                *(float4*)&a[rr][0] = *(const float4*)&sx[r0 + rr][kbase + k];
            #pragma unroll
            for (int j = 0; j < 4; ++j)
                *(float4*)&b[j][0] = *(const float4*)&sW[k + j][c0];
            #pragma unroll
            for (int j = 0; j < 4; ++j)
                #pragma unroll
                for (int rr = 0; rr < 4; ++rr)
                    #pragma unroll
                    for (int cc = 0; cc < 4; ++cc)
                        acc[rr][cc] += a[rr][j] * b[j][cc];
        }
    }

    #pragma unroll
    for (int rr = 0; rr < 4; ++rr) {
        int gr = row0 + r0 + rr;
        if (gr < N) {
            float s = dinv[gr];
            ushort4 o;
            o.x = f2b(acc[rr][0] * s); o.y = f2b(acc[rr][1] * s);
            o.z = f2b(acc[rr][2] * s); o.w = f2b(acc[rr][3] * s);
            *(ushort4*)&xws1b[gr * F1 + c0] = o;
        }
    }
}

// ---- gather1 + gemm2 fused. Round-17: LDS-diet (round-16) + cross-node
// software pipeline (round-15). History: r15 pipeline was NEUTRAL because the
// LDS pipe was saturated (~130 LDS instrs/node); r16 removed LDS saturation
// (17 instrs/node) but dropped the pipeline — latency-bound again. Now both:
// during node n's compute, node n+1's meta+csr+chunks 0,1 and node n's
// chunk 2 are in flight. ----
__global__ __launch_bounds__(256, 5) void gather1f(const int* __restrict__ csr,
                                                   const int* __restrict__ rowptr,
                                                   const int* __restrict__ deg,
                                                   const float* __restrict__ dinv,
                                                   const unsigned short* __restrict__ xb,
                                                   const float* __restrict__ b1,
                                                   const float* __restrict__ W2,
                                                   unsigned short* __restrict__ xws2b,
                                                   int N) {
    __shared__ float h1s[4][F1];     // per-wave staging, 1 KB
    int tid = threadIdx.x;
    int wv = tid >> 6, lane = tid & 63;
    int grp = lane >> 3;             // edge slot 0..7
    int fb = (lane & 7) << 3;        // feature base (8 features/lane in gather)
    int b3 = (lane >> 3) & 1, b4 = (lane >> 4) & 1, b5 = lane >> 5;
    int f = fb + b3 * 4 + b4 * 2 + b5;   // feature owned after reduce-scatter (bijection)
    float breg = b1[f];
    int c = lane & 31, half = b5;
    int k0 = half * 32;
    // W2 column slice in registers: wreg[j] = W2[k0+j][c]  (once per block)
    float wreg[32];
    #pragma unroll
    for (int j = 0; j < 32; ++j) wreg[j] = W2[(k0 + j) * F2 + c];

    int stride = gridDim.x * 4;
    int node = blockIdx.x * 4 + wv;

    // ---- prologue: node's meta + chunks 0,1 ----
    int start = 0, cnt = 0;
    float dd = 0.f;
    bool p0 = false, p1 = false;
    uint4 v0, v1;
    if (node < N) {
        start = rfl(rowptr[node]); cnt = rfl(deg[node]); dd = dinv[node];
        p0 = grp < cnt; p1 = grp + 8 < cnt;
        int s0 = 0, s1 = 0;
        if (p0) s0 = csr[start + grp];
        if (p1) s1 = csr[start + grp + 8];
        if (p0) v0 = *(const uint4*)(xb + (size_t)s0 * F1 + fb);
        if (p1) v1 = *(const uint4*)(xb + (size_t)s1 * F1 + fb);
    }

    while (node < N) {
        // ---- issue phase: next node's meta + chunks 0,1; current chunk 2; self ----
        int nnode = node + stride;
        int nstart = 0, ncnt = 0;
        float ndd = 0.f;
        bool np0 = false, np1 = false;
        uint4 nv0, nv1;
        if (nnode < N) {
            nstart = rfl(rowptr[nnode]); ncnt = rfl(deg[nnode]); ndd = dinv[nnode];
            np0 = grp < ncnt; np1 = grp + 8 < ncnt;
            int ns0 = 0, ns1 = 0;
            if (np0) ns0 = csr[nstart + grp];
            if (np1) ns1 = csr[nstart + grp + 8];
            if (np0) nv0 = *(const uint4*)(xb + (size_t)ns0 * F1 + fb);
            if (np1) nv1 = *(const uint4*)(xb + (size_t)ns1 * F1 + fb);
        }
        bool p2 = (16 + grp) < cnt;    // P(deg>16)~43%
        uint4 v2;
        if (p2) {
            int s2 = csr[start + 16 + grp];
            v2 = *(const uint4*)(xb + (size_t)s2 * F1 + fb);
        }
        uint4 vs = *(const uint4*)(xb + (size_t)node * F1 + fb);  // self row

        // ---- compute phase ----
        float acc[8] = {};
        if (p0) acc8(acc, v0);
        if (p1) acc8(acc, v1);
        if (p2) acc8(acc, v2);
        for (int j = 24; j < cnt; j += 8) {   // rare tail: deg>24 (~2%)
            int e = j + grp;
            if (e < cnt) {
                int s = csr[start + e];
                uint4 w = *(const uint4*)(xb + (size_t)s * F1 + fb);
                acc8(acc, w);
            }
        }
        if (grp == 0) acc8(acc, vs);   // self-loop, exactly once

        // reduce-scatter over grp bits: xor8 (4 shfl), xor16 (2), xor32 (1)
        float L[4];
        #pragma unroll
        for (int i = 0; i < 4; ++i) {
            float s = b3 ? acc[i] : acc[i + 4];
            float r = __shfl_xor(s, 8, 64);
            L[i] = (b3 ? acc[i + 4] : acc[i]) + r;
        }
        float M[2];
        #pragma unroll
        for (int i = 0; i < 2; ++i) {
            float s = b4 ? L[i] : L[i + 2];
            float r = __shfl_xor(s, 16, 64);
            M[i] = (b4 ? L[i + 2] : L[i]) + r;
        }
        float sx_ = b5 ? M[0] : M[1];
        float rx = __shfl_xor(sx_, 32, 64);
        float hv = (b5 ? M[1] : M[0]) + rx;

        hv = fmaxf(dd * hv + breg, 0.f);   // bias+relu in-register
        h1s[wv][f] = hv;                   // 1 scatter write (bijective -> conflict-free)

        // GEMV: dot(h1[k0..k0+31], wreg); k split across wave halves
        float dot = 0.f;
        #pragma unroll
        for (int t = 0; t < 8; ++t) {
            float4 hb = *(const float4*)&h1s[wv][k0 + t * 4];
            dot += hb.x * wreg[t * 4] + hb.y * wreg[t * 4 + 1]
                 + hb.z * wreg[t * 4 + 2] + hb.w * wreg[t * 4 + 3];
        }
        dot += __shfl_xor(dot, 32, 64);
        if (half == 0) xws2b[node * F2 + c] = f2b(dot * dd);

        // rotate pipeline state
        node = nnode; start = nstart; cnt = ncnt; dd = ndd;
        p0 = np0; p1 = np1; v0 = nv0; v1 = nv1;
    }
}

// ---- gather2 + gemm3 fused. LDS-diet + pipeline: next node's meta + csr +
// both chunks (32 edges, P(deg>32)~0.01%) in flight under current compute.
// Wl 2-column slice in 64 VGPRs; `out` via NON-TEMPORAL stores. ----
__global__ __launch_bounds__(256, 4) void gather2f(const int* __restrict__ csr,
                                                   const int* __restrict__ rowptr,
                                                   const int* __restrict__ deg,
                                                   const float* __restrict__ dinv,
                                                   const unsigned short* __restrict__ xb,
                                                   const float* __restrict__ b2,
                                                   const float* __restrict__ Wl,
                                                   const float* __restrict__ bl,
                                                   float* __restrict__ out, int N) {
    __shared__ float h2s[4][F2];     // per-wave staging, 512 B
    int tid = threadIdx.x;
    int wv = tid >> 6, lane = tid & 63;
    int grp = lane >> 2;             // edge slot 0..15
    int fb = (lane & 3) << 3;        // feature base (8 features/lane in gather)
    int bb2 = (lane >> 2) & 1, b3 = (lane >> 3) & 1, b4 = (lane >> 4) & 1, b5 = lane >> 5;
    int f = fb + bb2 * 4 + b3 * 2 + b4;  // feature owned after reduce-scatter (dup over b5)
    float breg = b2[f];
    float blA = bl[lane], blB = bl[lane + 64];
    // Wl 2-column slice in registers: wregA[j]=Wl[j][lane], wregB[j]=Wl[j][lane+64]
    float wregA[32], wregB[32];
    #pragma unroll
    for (int j = 0; j < 32; ++j) {
        wregA[j] = Wl[j * F0 + lane];
        wregB[j] = Wl[j * F0 + lane + 64];
    }

    int stride = gridDim.x * 4;
    int node = blockIdx.x * 4 + wv;

    int start = 0, cnt = 0;
    float dd = 0.f;
    bool p0 = false, p1 = false;
    uint4 v0, v1;
    if (node < N) {
        start = rfl(rowptr[node]); cnt = rfl(deg[node]); dd = dinv[node];
        p0 = grp < cnt; p1 = grp + 16 < cnt;
        int s0 = 0, s1 = 0;
        if (p0) s0 = csr[start + grp];
        if (p1) s1 = csr[start + grp + 16];
        if (p0) v0 = *(const uint4*)(xb + (size_t)s0 * F2 + fb);
        if (p1) v1 = *(const uint4*)(xb + (size_t)s1 * F2 + fb);
    }

    while (node < N) {
        int nnode = node + stride;
        int nstart = 0, ncnt = 0;
        float ndd = 0.f;
        bool np0 = false, np1 = false;
        uint4 nv0, nv1;
        if (nnode < N) {
            nstart = rfl(rowptr[nnode]); ncnt = rfl(deg[nnode]); ndd = dinv[nnode];
            np0 = grp < ncnt; np1 = grp + 16 < ncnt;
            int ns0 = 0, ns1 = 0;
            if (np0) ns0 = csr[nstart + grp];
            if (np1) ns1 = csr[nstart + grp + 16];
            if (np0) nv0 = *(const uint4*)(xb + (size_t)ns0 * F2 + fb);
            if (np1) nv1 = *(const uint4*)(xb + (size_t)ns1 * F2 + fb);
        }
        uint4 vs = *(const uint4*)(xb + (size_t)node * F2 + fb);  // self row

        float acc[8] = {};
        if (p0) acc8(acc, v0);
        if (p1) acc8(acc, v1);
        for (int j = 32; j < cnt; j += 16) {   // ultra-rare tail: deg>32
            int e = j + grp;
            if (e < cnt) {
                int s = csr[start + e];
                uint4 w = *(const uint4*)(xb + (size_t)s * F2 + fb);
                acc8(acc, w);
            }
        }
        if (grp == 0) acc8(acc, vs);   // self-loop

        // reduce-scatter over grp bits: xor4 (4), xor8 (2), xor16 (1), xor32 (1)
        float L[4];
        #pragma unroll
        for (int i = 0; i < 4; ++i) {
            float s = bb2 ? acc[i] : acc[i + 4];
            float r = __shfl_xor(s, 4, 64);
            L[i] = (bb2 ? acc[i + 4] : acc[i]) + r;
        }
        float M[2];
        #pragma unroll
        for (int i = 0; i < 2; ++i) {
            float s = b3 ? L[i] : L[i + 2];
            float r = __shfl_xor(s, 8, 64);
            M[i] = (b3 ? L[i + 2] : L[i]) + r;
        }
        float sx_ = b4 ? M[0] : M[1];
        float rx = __shfl_xor(sx_, 16, 64);
        float hv = (b4 ? M[1] : M[0]) + rx;
        hv += __shfl_xor(hv, 32, 64);      // both halves now hold full sum for f

        hv = fmaxf(dd * hv + breg, 0.f);
        if (!b5) h2s[wv][f] = hv;          // 32 distinct banks -> conflict-free

        // final GEMV: out[c] = dot(h2[0..31], Wl[:,c]) + bl, c = lane and lane+64
        float dA = 0.f, dB = 0.f;
        #pragma unroll
        for (int t = 0; t < 8; ++t) {
            float4 hb = *(const float4*)&h2s[wv][t * 4];
            dA += hb.x * wregA[t * 4] + hb.y * wregA[t * 4 + 1]
                + hb.z * wregA[t * 4 + 2] + hb.w * wregA[t * 4 + 3];
            dB += hb.x * wregB[t * 4] + hb.y * wregB[t * 4 + 1]
                + hb.z * wregB[t * 4 + 2] + hb.w * wregB[t * 4 + 3];
        }
        size_t ob = (size_t)node * F0;
        __builtin_nontemporal_store(dA + blA, &out[ob + lane]);
        __builtin_nontemporal_store(dB + blB, &out[ob + lane + 64]);

        node = nnode; start = nstart; cnt = ncnt; dd = ndd;
        p0 = np0; p1 = np1; v0 = nv0; v1 = nv1;
    }
}

extern "C" void kernel_launch(void* const* d_in, const int* in_sizes, int n_in,
                              void* d_out, int out_size, void* d_ws, size_t ws_size,
                              hipStream_t stream) {
    const float* x  = (const float*)d_in[0];
    const int*   ei = (const int*)d_in[1];
    const float* W1 = (const float*)d_in[2];
    const float* b1 = (const float*)d_in[3];
    const float* W2 = (const float*)d_in[4];
    const float* b2 = (const float*)d_in[5];
    const float* Wl = (const float*)d_in[6];
    const float* bl = (const float*)d_in[7];
    float* out = (float*)d_out;

    const int N = in_sizes[0] / F0;   // 50000
    const int E = in_sizes[1] / 2;    // 800000
    const int* src = ei;
    const int* dst = ei + E;
    const int NB = (N + 255) / 256;   // 196

    char* ws = (char*)d_ws;
    size_t off = 0;
    auto alloc = [&](size_t bytes) {
        void* p = ws + off;
        off += (bytes + 255) & ~(size_t)255;
        return p;
    };
    int*            deg    = (int*)alloc((size_t)N * 4);
    float*          dinv   = (float*)alloc((size_t)N * 4);
    int*            rowptr = (int*)alloc((size_t)N * 4);
    int*            cursor = (int*)alloc((size_t)N * 4);
    int*            bsum   = (int*)alloc((size_t)NB * 4);
    int*            boff   = (int*)alloc((size_t)NB * 4);
    int*            csr    = (int*)alloc((size_t)E * 4);
    unsigned short* xws1b  = (unsigned short*)alloc((size_t)N * F1 * 2);
    unsigned short* xws2b  = (unsigned short*)alloc((size_t)N * F2 * 2);

    hipMemsetAsync(deg, 0, (size_t)N * 4, stream);
    deg_count<<<(E + 255) / 256, 256, 0, stream>>>(dst, deg, E);
    scan1<<<NB, 256, 0, stream>>>(deg, dinv, rowptr, bsum, N);
    scan2<<<1, 256, 0, stream>>>(bsum, boff, NB);
    scan3<<<NB, 256, 0, stream>>>(rowptr, boff, cursor, N);
    bucket8<<<1024, 256, 0, stream>>>(src, dst, cursor, csr, E, N);

    gemm1<<<(N + 63) / 64, 256, 0, stream>>>(x, W1, dinv, xws1b, N, 64);
    gather1f<<<2048, 256, 0, stream>>>(csr, rowptr, deg, dinv, xws1b, b1, W2, xws2b, N);
    gather2f<<<2048, 256, 0, stream>>>(csr, rowptr, deg, dinv, xws2b, b2, Wl, bl, out, N);
}